// Round 9
// baseline (171.104 us; speedup 1.0000x reference)
//
#include <hip/hip_runtime.h>

#define BN 4
#define CH 64          // CIN*UM = COUT*UM
#define HH 128
#define WW 128
#define PIX (HH*WW)

// workspace layout (float offsets)
#define OFF_WL  0                    // [64][9][64]  = 36864
#define OFF_S   36864                // [2][64]      = 128
#define OFF_AVG 36992                // [4][2][128][128] = 131072

__device__ __forceinline__ int iclamp(int v, int lo, int hi) {
    return v < lo ? lo : (v > hi ? hi : v);
}

// ---- single prep kernel, 3 roles by block range:
//  [0,144)    : Wl[c][tap][oc] = ker[oc, c, p, q], tap = q*3+p
//  144        : S[u][oc] via factorized sum (== sum of Wl over i,taps)
//  [145, 657) : avg[b][u][16x16 tile] via halo colsum + box3x3, /288
__global__ __launch_bounds__(256) void k_prep(const float* __restrict__ params,
                                              const float* __restrict__ basis,
                                              const float* __restrict__ x,
                                              float* __restrict__ Wl,
                                              float* __restrict__ S,
                                              float* __restrict__ avg) {
    int bx = blockIdx.x;
    if (bx < 144) {
        int idx = bx * 256 + threadIdx.x;      // < 36864
        int oc  = idx & 63;
        int tap = (idx >> 6) % 9;
        int c   = idx / 576;
        int q = tap / 3, p = tap % 3;
        int o = oc >> 1, g = oc & 1;
        int i = c >> 1, u = c & 1;
        float s = 0.f;
        #pragma unroll
        for (int n = 0; n < 4; ++n)
            #pragma unroll
            for (int d = 0; d < 4; ++d)
                s = fmaf(params[((o * 32 + i) * 4 + n) * 4 + d],
                         basis[((((n * 4 + d) * 3 + p) * 3 + q) * 2 + g) * 2 + u], s);
        Wl[idx] = s;
    } else if (bx == 144) {
        int t = threadIdx.x;
        if (t < 128) {
            int u = t >> 6, oc = t & 63;
            int o = oc >> 1, g = oc & 1;
            float s = 0.f;
            #pragma unroll
            for (int nd = 0; nd < 16; ++nd) {
                int n = nd >> 2, d = nd & 3;
                float pa = 0.f;
                for (int i = 0; i < 32; ++i)
                    pa += params[((o * 32 + i) * 4 + n) * 4 + d];
                float sb = 0.f;
                #pragma unroll
                for (int e = 0; e < 3; ++e)
                    #pragma unroll
                    for (int f = 0; f < 3; ++f)
                        sb += basis[((((n * 4 + d) * 3 + e) * 3 + f) * 2 + g) * 2 + u];
                s = fmaf(pa, sb, s);
            }
            S[t] = s;
        }
    } else {
        // avg tile: id -> (b, u, tile)
        int id = bx - 145;                 // < 512
        int tile = id & 63;
        int u    = (id >> 6) & 1;
        int b    = id >> 7;
        int ty0 = (tile >> 3) * 16, tx0 = (tile & 7) * 16;

        __shared__ float hs[18][19];
        int t = threadIdx.x;
        for (int cell = t; cell < 324; cell += 256) {
            int hy = cell / 18, hx = cell - (cell / 18) * 18;
            int gy = iclamp(ty0 + hy - 1, 0, HH - 1);
            int gx = iclamp(tx0 + hx - 1, 0, WW - 1);
            const float* xp = x + ((size_t)b * CH + u) * PIX + gy * WW + gx;
            float s = 0.f;
            #pragma unroll
            for (int i = 0; i < 32; ++i) s += xp[(size_t)i * 2 * PIX];
            hs[hy][hx] = s;
        }
        __syncthreads();
        int py = t >> 4, px = t & 15;
        float s = hs[py][px]     + hs[py][px + 1]     + hs[py][px + 2]
                + hs[py + 1][px] + hs[py + 1][px + 1] + hs[py + 1][px + 2]
                + hs[py + 2][px] + hs[py + 2][px + 1] + hs[py + 2][px + 2];
        avg[(size_t)(b * 2 + u) * PIX + (ty0 + py) * WW + (tx0 + px)] = s * (1.0f / 288.0f);
    }
}

// ---- main: 1 pixel/thread, 8 oc/thread, 2048 blocks -> 32 waves/CU
__global__ __launch_bounds__(256, 8) void k_main(
    const float* __restrict__ x,     // [4][64][128][128]
    const float* __restrict__ Wl,    // [64][9][64]
    const float* __restrict__ S,     // [2][64]
    const float* __restrict__ bias,  // [64]
    const float* __restrict__ avg,   // [4][2][128][128]
    const float* __restrict__ bptr,  // scalar b
    float* __restrict__ out)         // [4][64][128][128]
{
    int tile   = blockIdx.x;          // 8x8 tiles of 16x16
    int ocbase = blockIdx.y * 8;
    int b      = blockIdx.z;
    int ty = threadIdx.x >> 4, tx = threadIdx.x & 15;
    int h = (tile >> 3) * 16 + ty;
    int w = (tile & 7) * 16 + tx;

    int hm = h > 0 ? h - 1 : 0, hp = h < HH - 1 ? h + 1 : HH - 1;
    int wm = w > 0 ? w - 1 : 0, wp = w < WW - 1 ? w + 1 : WW - 1;
    int rowoff[3] = { hm * WW, h * WW, hp * WW };
    int coloff[3] = { wm, w, wp };
    int off[9];
    #pragma unroll
    for (int r = 0; r < 3; ++r)
        #pragma unroll
        for (int p = 0; p < 3; ++p)
            off[r * 3 + p] = rowoff[r] + coloff[p];

    float acc[8];
    #pragma unroll
    for (int j = 0; j < 8; ++j) acc[j] = 0.f;

    const float* xc = x + (size_t)b * CH * PIX;
    const float* wc = Wl + ocbase;

    float xv[9];
    #pragma unroll
    for (int k = 0; k < 9; ++k) xv[k] = xc[off[k]];

    for (int c = 0; c < CH; ++c) {
        // prefetch next channel's window (consumed next iteration)
        const float* xn = xc + (c < CH - 1 ? PIX : 0);
        float xf[9];
        #pragma unroll
        for (int k = 0; k < 9; ++k) xf[k] = xn[off[k]];

        #pragma unroll
        for (int t = 0; t < 9; ++t) {
            const float* wt = wc + t * 64;
            float xt = xv[t];
            #pragma unroll
            for (int j = 0; j < 8; ++j)
                acc[j] = fmaf(xt, wt[j], acc[j]);   // wt block-uniform -> SGPR
        }
        #pragma unroll
        for (int k = 0; k < 9; ++k) xv[k] = xf[k];
        xc += PIX;
        wc += 576;
    }

    int pix = h * WW + w;
    float a0 = avg[(size_t)(b * 2 + 0) * PIX + pix];
    float a1 = avg[(size_t)(b * 2 + 1) * PIX + pix];
    float bthr = bptr[0];

    float* ob = out + (size_t)b * CH * PIX + pix;
    #pragma unroll
    for (int j = 0; j < 8; j += 2) {
        int oc = ocbase + j;
        float t0 = acc[j]     - a0 * S[oc]     - a1 * S[64 + oc]     + bias[oc];
        float t1 = acc[j + 1] - a0 * S[oc + 1] - a1 * S[64 + oc + 1] + bias[oc + 1];
        float n = sqrtf(t0 * t0 + t1 * t1);
        float r0, r1;
        if (n - bthr <= 0.f) { r0 = 0.f; r1 = 0.f; }
        else { r0 = t0 / n; r1 = t1 / n; }
        ob[(size_t)oc * PIX]       = r0 + a0;
        ob[(size_t)(oc + 1) * PIX] = r1 + a1;
    }
}

extern "C" void kernel_launch(void* const* d_in, const int* in_sizes, int n_in,
                              void* d_out, int out_size, void* d_ws, size_t ws_size,
                              hipStream_t stream) {
    const float* xx     = (const float*)d_in[0];
    const float* params = (const float*)d_in[1];
    const float* basis  = (const float*)d_in[2];
    const float* bias   = (const float*)d_in[3];
    const float* bptr   = (const float*)d_in[4];
    float* out = (float*)d_out;
    float* ws  = (float*)d_ws;

    float* Wl  = ws + OFF_WL;
    float* S   = ws + OFF_S;
    float* avg = ws + OFF_AVG;

    k_prep<<<657, 256, 0, stream>>>(params, basis, xx, Wl, S, avg);

    dim3 grid(64, 8, BN);
    k_main<<<grid, 256, 0, stream>>>(xx, Wl, S, bias, avg, bptr, out);
}